// Round 5
// baseline (262.085 us; speedup 1.0000x reference)
//
#include <hip/hip_runtime.h>

// out[n,c,h,w] = sum_{5x5 in-bounds taps} exp(-0.5*||xyz_nbr - xyz_ctr||^2)
//                * mask_nbr * softmax[n,c,nbr]
// OOB taps have weight forced to 0, so loads only need SAFE (clamped)
// addresses; clamped-slot garbage is multiplied by 0.0f.
//
// R9 resubmit (R4 bench failed on container acquisition, not the kernel).
// Barrier-free / LDS-free. R5-R8 showed the two-phase LDS+barrier
// structure pins VALUBusy at ~22% regardless of occupancy (R7) or load
// batching (R8): every wave stalls collectively at the barrier and the
// phase-2 load stampede serializes. Real work is ~26us VALU + ~23us HBM,
// measured 117-137us => pure exposed latency.
// New mapping: 1 lane = 1 pixel, ALL 20 channels. The pixel's 25 weights
// live in 25 VGPRs (computed once, no sharing needed -> no LDS, no
// __syncthreads, fully independent waves). Channel loop rolled (unroll 2),
// 25 coalesced scalar window loads per channel (clamped col offsets
// precomputed; row bases wave-uniform -> SGPR), dual accumulators.
// __launch_bounds__(256,5): VGPR cap ~102 >> est. need ~60-90 (R6/R7:
// never cap below natural need), blocks occupancy-killing 128-bloat.
// 1D grid ONLY (2D gridDim.y broke harness graph replay in R3).

#define H_DIM 64
#define W_DIM 2048
#define C_DIM 20
#define N_DIM 8
#define HW (H_DIM * W_DIM)
#define BLOCK 256

__global__ __launch_bounds__(BLOCK, 5) void lcx_kernel(
    const float* __restrict__ xyz,
    const float* __restrict__ sm,
    const int*  __restrict__ mask,
    float* __restrict__ out)
{
    const int b  = blockIdx.x;            // 4096 blocks: 8 wchunks x 64 h x 8 n
    const int wc = b & 7;
    const int h  = (b >> 3) & (H_DIM - 1);
    const int n  = b >> 9;
    const int px = (wc << 8) + threadIdx.x;   // this lane's pixel column

    const float* xyzn  = xyz  + n * 3 * HW;
    const int*   maskn = mask + n * HW;

    // ---------------- Phase A: 25 weights in registers ----------------
    float w[25];
    {
        const int ctr = h * W_DIM + px;
        const float cx = xyzn[ctr];
        const float cy = xyzn[HW + ctr];
        const float cz = xyzn[2 * HW + ctr];
        const bool interior = (px >= 2) && (px <= W_DIM - 3);

        #pragma unroll
        for (int r = 0; r < 5; ++r) {
            const int hi = h + r - 2;
            if ((unsigned)hi >= (unsigned)H_DIM) {
                #pragma unroll
                for (int dj = 0; dj < 5; ++dj) w[r * 5 + dj] = 0.0f;
            } else {
                const int rb = hi * W_DIM;
                if (interior) {
                    const int o = rb + px - 2;
                    const float4 xv = *(const float4*)(xyzn + o);
                    const float  xs = xyzn[o + 4];
                    const float4 yv = *(const float4*)(xyzn + HW + o);
                    const float  ys = xyzn[HW + o + 4];
                    const float4 zv = *(const float4*)(xyzn + 2 * HW + o);
                    const float  zs = xyzn[2 * HW + o + 4];
                    const int4   mv = *(const int4*)(maskn + o);
                    const int    ms = maskn[o + 4];
                    const float nx[5] = {xv.x, xv.y, xv.z, xv.w, xs};
                    const float ny[5] = {yv.x, yv.y, yv.z, yv.w, ys};
                    const float nz[5] = {zv.x, zv.y, zv.z, zv.w, zs};
                    const int   nm[5] = {mv.x, mv.y, mv.z, mv.w, ms};
                    #pragma unroll
                    for (int dj = 0; dj < 5; ++dj) {
                        const float dx = nx[dj] - cx;
                        const float dy = ny[dj] - cy;
                        const float dz = nz[dj] - cz;
                        const float d2 = fmaf(dx, dx, fmaf(dy, dy, dz * dz));
                        w[r * 5 + dj] = (nm[dj] != 0) ? __expf(-0.5f * d2) : 0.0f;
                    }
                } else {
                    #pragma unroll
                    for (int dj = 0; dj < 5; ++dj) {
                        const int col = px + dj - 2;
                        const bool cok = ((unsigned)col < (unsigned)W_DIM);
                        const int cc  = cok ? col : (col < 0 ? 0 : W_DIM - 1);
                        const int o   = rb + cc;
                        const float dx = xyzn[o] - cx;
                        const float dy = xyzn[HW + o] - cy;
                        const float dz = xyzn[2 * HW + o] - cz;
                        const float d2 = fmaf(dx, dx, fmaf(dy, dy, dz * dz));
                        const bool ok = cok && (maskn[o] != 0);
                        w[r * 5 + dj] = ok ? __expf(-0.5f * d2) : 0.0f;
                    }
                }
            }
        }
    }

    // ---------------- Phase B: 20 channels, 25 taps each ----------------
    // clamped column indices (weights are 0 wherever the clamp engaged)
    int coff[5];
    #pragma unroll
    for (int dj = 0; dj < 5; ++dj) {
        const int col = px + dj - 2;
        coff[dj] = (col < 0) ? 0 : (col > W_DIM - 1 ? W_DIM - 1 : col);
    }
    // clamped row bases: wave-uniform (h is per-block) -> SGPRs
    int rbc[5];
    #pragma unroll
    for (int r = 0; r < 5; ++r) {
        const int hi = h + r - 2;
        rbc[r] = ((hi < 0) ? 0 : (hi >= H_DIM ? H_DIM - 1 : hi)) * W_DIM;
    }

    const float* smn  = sm  + n * C_DIM * HW;
    float*       outn = out + n * C_DIM * HW;
    const int octr = h * W_DIM + px;

    #pragma unroll 2
    for (int c = 0; c < C_DIM; ++c) {
        const float* pc = smn + c * HW;
        float a0 = 0.0f, a1 = 0.0f;
        #pragma unroll
        for (int r = 0; r < 5; ++r) {
            const float* pr = pc + rbc[r];
            const float s0 = pr[coff[0]];
            const float s1 = pr[coff[1]];
            const float s2 = pr[coff[2]];
            const float s3 = pr[coff[3]];
            const float s4 = pr[coff[4]];
            a0 = fmaf(w[r * 5 + 0], s0, a0);
            a1 = fmaf(w[r * 5 + 1], s1, a1);
            a0 = fmaf(w[r * 5 + 2], s2, a0);
            a1 = fmaf(w[r * 5 + 3], s3, a1);
            a0 = fmaf(w[r * 5 + 4], s4, a0);
        }
        outn[c * HW + octr] = a0 + a1;
    }
}

extern "C" void kernel_launch(void* const* d_in, const int* in_sizes, int n_in,
                              void* d_out, int out_size, void* d_ws, size_t ws_size,
                              hipStream_t stream)
{
    const float* xyz  = (const float*)d_in[0];
    const float* sm   = (const float*)d_in[1];
    const int*   mask = (const int*)d_in[2];
    float*       out  = (float*)d_out;

    const int grid = 8 * H_DIM * N_DIM;   // 4096 blocks, 1D ONLY

    lcx_kernel<<<grid, BLOCK, 0, stream>>>(xyz, sm, mask, out);
}

// Round 6
// 221.399 us; speedup vs baseline: 1.1838x; 1.1838x over previous
//
#include <hip/hip_runtime.h>

// out[n,c,h,w] = sum_{5x5 in-bounds taps} exp(-0.5*||xyz_nbr - xyz_ctr||^2)
//                * mask_nbr * softmax[n,c,nbr]
//
// R10 = R5 (best measured, 117us) with phase 1 de-latencied.
// R5-R9 post-mortems: VALUBusy pinned 13-22% across five structures;
// occupancy (R7 39%, R9 44%) and batching (R8) don't move duration ->
// the exposed latency is phase 1's ~43 dependent global loads/thread
// (7x redundant across the wave, 5 serialized exposures feeding exp).
// R10:
//   Phase 0: stage xyz halo (3 comps x 5 rows x 264 cols) into LDS with
//            ~4 independent coalesced float4 loads/thread (ONE latency
//            exposure). mask is folded into staged x: masked -> 1e30 =>
//            d2 = inf => __expf(-inf) = 0 (no NaN: center always finite,
//            read from global). Clamped f4 base; mis-placed slots only
//            ever correspond to OOB columns whose weight is forced 0.
//   Phase 1': weights from conflict-free ds_read_b32 (lane-consecutive),
//            zero global loads.
//   Phase 2: EXACTLY R5 (4px x 5ch/thread, f2/f4/f2 windows, b128 wt).
// LDS 41.4 KB -> 3 blocks/CU. Plain __launch_bounds__ (R6/R7: min-waves
// bounds below natural need cause catastrophic scratch spill).
// 1D grid ONLY (2D gridDim.y broke harness graph replay in R3).

#define H_DIM 64
#define W_DIM 2048
#define C_DIM 20
#define N_DIM 8
#define HW (H_DIM * W_DIM)
#define BLOCK 256
#define SPAN 264           // staged cols: [w0-4 .. w0+259], f4-aligned
#define NG   66            // f4 groups per (comp,row)

__global__ __launch_bounds__(BLOCK) void lcx_kernel(
    const float* __restrict__ xyz,
    const float* __restrict__ sm,
    const int*  __restrict__ mask,
    float* __restrict__ out)
{
    __shared__ float xyz_s[3][5][SPAN];   // 15.84 KB, mask folded into x
    __shared__ float w_lds[25 * BLOCK];   // 25.6 KB

    const int b  = blockIdx.x;            // 4096 blocks: 8 wchunks x 64 h x 8 n
    const int wc = b & 7;
    const int h  = (b >> 3) & (H_DIM - 1);
    const int n  = b >> 9;
    const int w0 = wc << 8;               // 256-pixel chunk base
    const int t  = threadIdx.x;

    const float* xyzn  = xyz  + n * 3 * HW;
    const int*   maskn = mask + n * HW;

    // center coords from global (must NOT be mask-folded), issued early
    const int ctr = h * W_DIM + w0 + t;
    const float cx = xyzn[ctr];
    const float cy = xyzn[HW + ctr];
    const float cz = xyzn[2 * HW + ctr];

    // ---------------- Phase 0: stage xyz halo into LDS ----------------
    // jobs: comp(3) x row(5) x grp(66) = 990 float4 stores
    #pragma unroll
    for (int it = 0; it < 4; ++it) {
        const int j = t + (it << 8);
        if (j < 3 * 5 * NG) {
            const int rem  = j / NG;          // 0..14
            const int grp  = j - rem * NG;    // 0..65
            const int comp = rem % 3;
            const int row  = rem / 3;
            const int hi   = h + row - 2;
            const int hic  = (hi < 0) ? 0 : (hi >= H_DIM ? H_DIM - 1 : hi);
            int gc = w0 - 4 + (grp << 2);
            gc = (gc < 0) ? 0 : (gc > W_DIM - 4 ? W_DIM - 4 : gc);
            const int o = hic * W_DIM + gc;
            float4 v = *(const float4*)(xyzn + comp * HW + o);
            if (comp == 0) {                  // fold mask into x
                const int4 m = *(const int4*)(maskn + o);
                v.x = m.x ? v.x : 1e30f;
                v.y = m.y ? v.y : 1e30f;
                v.z = m.z ? v.z : 1e30f;
                v.w = m.w ? v.w : 1e30f;
            }
            *(float4*)&xyz_s[comp][row][grp << 2] = v;
        }
    }
    __syncthreads();

    // -------- Phase 1': 25 weights from LDS (zero global loads) --------
    {
        #pragma unroll
        for (int r = 0; r < 5; ++r) {
            const int hi  = h + r - 2;
            const bool rok = ((unsigned)hi < (unsigned)H_DIM);
            float w5[5];
            #pragma unroll
            for (int dj = 0; dj < 5; ++dj) {
                const int col = w0 + t + dj - 2;
                const bool cok = ((unsigned)col < (unsigned)W_DIM);
                const int s   = t + dj + 2;      // col - (w0-4)
                const float xv = xyz_s[0][r][s]; // 1e30 if masked
                const float yv = xyz_s[1][r][s];
                const float zv = xyz_s[2][r][s];
                const float dx = xv - cx;
                const float dy = yv - cy;
                const float dz = zv - cz;
                const float d2 = fmaf(dx, dx, fmaf(dy, dy, dz * dz));
                w5[dj] = (rok && cok) ? __expf(-0.5f * d2) : 0.0f;
            }
            #pragma unroll
            for (int dj = 0; dj < 5; ++dj)
                w_lds[(r * 5 + dj) * BLOCK + t] = w5[dj];
        }
    }
    __syncthreads();

    // ------------- Phase 2: 4 pixels x 5 channels per thread (R5) -------------
    const int cg = t >> 6;                // 0..3, wave-uniform channel group
    const int q  = t & 63;                // pixel-quad within chunk
    const int wq = w0 + (q << 2);         // base col of this thread's 4 pixels

    const float* smn  = sm  + (n * C_DIM + cg * 5) * HW;
    float*       outn = out + (n * C_DIM + cg * 5) * HW;

    // window cols [wq-2 .. wq+5]: f2 @ b0, f4 @ b1, f2 @ b2. Slots holding
    // clamped garbage are only ever multiplied by zero weights.
    const int b0 = (wq >= 2) ? (wq - 2) : 0;                        // float2
    const int b1 = wq;                                              // float4
    const int b2 = (wq + 4 <= W_DIM - 2) ? (wq + 4) : (W_DIM - 2);  // float2

    float4 acc[5];
    #pragma unroll
    for (int c = 0; c < 5; ++c) acc[c] = make_float4(0.f, 0.f, 0.f, 0.f);

    #pragma unroll
    for (int r = 0; r < 5; ++r) {
        const int hi  = h + r - 2;
        const int hic = (hi < 0) ? 0 : (hi >= H_DIM ? H_DIM - 1 : hi);
        const int rbc = hic * W_DIM;      // weights are 0 for OOB rows

        // 5 taps x 4 pixels of weights, conflict-free b128 reads
        float4 wt[5];
        #pragma unroll
        for (int dj = 0; dj < 5; ++dj)
            wt[dj] = *(const float4*)&w_lds[(r * 5 + dj) * BLOCK + (q << 2)];

        #pragma unroll
        for (int c = 0; c < 5; ++c) {
            const float* pr = smn + c * HW + rbc;
            const float2 f0 = *(const float2*)(pr + b0);
            const float4 f1 = *(const float4*)(pr + b1);
            const float2 f2 = *(const float2*)(pr + b2);
            float fs[8];
            fs[0]=f0.x; fs[1]=f0.y; fs[2]=f1.x; fs[3]=f1.y;
            fs[4]=f1.z; fs[5]=f1.w; fs[6]=f2.x; fs[7]=f2.y;

            #pragma unroll
            for (int dj = 0; dj < 5; ++dj) {
                acc[c].x = fmaf(wt[dj].x, fs[0 + dj], acc[c].x);
                acc[c].y = fmaf(wt[dj].y, fs[1 + dj], acc[c].y);
                acc[c].z = fmaf(wt[dj].z, fs[2 + dj], acc[c].z);
                acc[c].w = fmaf(wt[dj].w, fs[3 + dj], acc[c].w);
            }
        }
    }

    const int octr = h * W_DIM + wq;
    #pragma unroll
    for (int c = 0; c < 5; ++c)
        *(float4*)(outn + c * HW + octr) = acc[c];
}

extern "C" void kernel_launch(void* const* d_in, const int* in_sizes, int n_in,
                              void* d_out, int out_size, void* d_ws, size_t ws_size,
                              hipStream_t stream)
{
    const float* xyz  = (const float*)d_in[0];
    const float* sm   = (const float*)d_in[1];
    const int*   mask = (const int*)d_in[2];
    float*       out  = (float*)d_out;

    const int grid = 8 * H_DIM * N_DIM;   // 4096 blocks, 1D ONLY

    lcx_kernel<<<grid, BLOCK, 0, stream>>>(xyz, sm, mask, out);
}